// Round 7
// baseline (201.001 us; speedup 1.0000x reference)
//
#include <hip/hip_runtime.h>

typedef float f32x4 __attribute__((ext_vector_type(4)));

#define V_THRESH 1.0f
#define TAU_REFRAC 0.1f
#define BLOCK 256

// Process 4 lanes of a float4 (compile-time indexed -> registers).
__device__ __forceinline__ void neuron4(const f32x4 im, const f32x4 me,
                                        const f32x4 rf, const f32x4 pl,
                                        const f32x4 ps, const f32x4 sc,
                                        float t, float t_end,
                                        f32x4& vsp, f32x4& vmem, f32x4& vrf,
                                        f32x4& vpl, f32x4& vps, f32x4& vsc,
                                        f32x4& vst, float& lmax) {
    #pragma unroll
    for (int j = 0; j < 4; ++j) {
        float imp = im[j], m0 = me[j], r0 = rf[j];
        float p0 = pl[j], s0 = ps[j], c0 = sc[j];
        float mi = (r0 > t) ? 0.0f : imp;      // masked impulse
        float nm = m0 + mi;                    // new_mem
        bool spiked = (nm >= V_THRESH);
        float sp = spiked ? 1.0f : 0.0f;
        float resid = nm - V_THRESH;
        float new_pl = resid - s0;             // two-step, matches reference rounding
        vsp[j]  = sp * V_THRESH;
        vmem[j] = nm - V_THRESH * sp;          // reset by subtraction
        vpl[j]  = spiked ? new_pl : p0;
        vps[j]  = spiked ? (s0 + new_pl) : s0;
        vrf[j]  = spiked ? t_end : r0;
        float c1 = c0 + sp;
        vsc[j]  = c1;
        vst[j]  = t * sp;
        lmax = fmaxf(lmax, c1);
    }
}

// One float4 per thread per plane, no loop: max TLP, no loop-carried deps.
// Block max goes to block_max[blockIdx.x] (no same-address atomics).
__global__ __launch_bounds__(BLOCK) void spike_kernel(
    const f32x4* __restrict__ impulse,
    const f32x4* __restrict__ mem,
    const f32x4* __restrict__ refrac,
    const f32x4* __restrict__ payloads,
    const f32x4* __restrict__ paysum,
    const f32x4* __restrict__ spikecounts,
    const float* __restrict__ time,
    f32x4* __restrict__ out,           // 7 contiguous planes, n4 float4 each
    float* __restrict__ block_max,     // ws: one slot per block, always written
    int n4)
{
    const float t = time[0];
    const float t_end = t + TAU_REFRAC;

    float lmax = -__builtin_inff();
    const size_t i = (size_t)blockIdx.x * BLOCK + threadIdx.x;

    if (i < (size_t)n4) {
        f32x4 im = impulse[i];
        f32x4 me = mem[i];
        f32x4 rf = refrac[i];
        f32x4 pl = payloads[i];
        f32x4 ps = paysum[i];
        f32x4 sc = spikecounts[i];
        f32x4 vsp, vmem, vrf, vpl, vps, vsc, vst;

        neuron4(im, me, rf, pl, ps, sc, t, t_end,
                vsp, vmem, vrf, vpl, vps, vsc, vst, lmax);

        out[i]                  = vsp;
        out[i +     (size_t)n4] = vmem;
        out[i + 2 * (size_t)n4] = vrf;
        out[i + 3 * (size_t)n4] = vpl;
        out[i + 4 * (size_t)n4] = vps;
        out[i + 5 * (size_t)n4] = vsc;
        out[i + 6 * (size_t)n4] = vst;
    }

    // Block-level max reduce: wave butterfly -> LDS -> thread 0 stores.
    #pragma unroll
    for (int off = 32; off > 0; off >>= 1)
        lmax = fmaxf(lmax, __shfl_xor(lmax, off));

    __shared__ float wmax[BLOCK / 64];
    if ((threadIdx.x & 63) == 0)
        wmax[threadIdx.x >> 6] = lmax;
    __syncthreads();
    if (threadIdx.x == 0) {
        float m = fmaxf(fmaxf(wmax[0], wmax[1]), fmaxf(wmax[2], wmax[3]));
        block_max[blockIdx.x] = m;
    }
}

__global__ __launch_bounds__(256) void finalize_kernel(
    const float* __restrict__ block_max,
    const float* __restrict__ time,
    float* __restrict__ out_scalar,
    int nblocks)
{
    float lmax = -__builtin_inff();
    for (int i = threadIdx.x; i < nblocks; i += 256)
        lmax = fmaxf(lmax, block_max[i]);
    #pragma unroll
    for (int off = 32; off > 0; off >>= 1)
        lmax = fmaxf(lmax, __shfl_xor(lmax, off));
    __shared__ float wmax[4];
    if ((threadIdx.x & 63) == 0)
        wmax[threadIdx.x >> 6] = lmax;
    __syncthreads();
    if (threadIdx.x == 0) {
        float m = fmaxf(fmaxf(wmax[0], wmax[1]), fmaxf(wmax[2], wmax[3]));
        out_scalar[0] = m * (1.0f / time[0]);
    }
}

extern "C" void kernel_launch(void* const* d_in, const int* in_sizes, int n_in,
                              void* d_out, int out_size, void* d_ws, size_t ws_size,
                              hipStream_t stream) {
    const f32x4* impulse     = (const f32x4*)d_in[0];
    const f32x4* mem         = (const f32x4*)d_in[1];
    const f32x4* refrac      = (const f32x4*)d_in[2];
    const f32x4* payloads    = (const f32x4*)d_in[3];
    const f32x4* paysum      = (const f32x4*)d_in[4];
    const f32x4* spikecounts = (const f32x4*)d_in[5];
    const float* time        = (const float*)d_in[6];

    const int n  = in_sizes[0];      // 16777216
    const int n4 = n / 4;            // 4194304
    float* out = (float*)d_out;
    float* block_max = (float*)d_ws; // nblocks floats, fully rewritten each call

    const int nblocks = (n4 + BLOCK - 1) / BLOCK;   // 16384 (64 KB of ws)

    spike_kernel<<<nblocks, BLOCK, 0, stream>>>(impulse, mem, refrac, payloads,
                                                paysum, spikecounts, time,
                                                (f32x4*)out, block_max, n4);
    finalize_kernel<<<1, 256, 0, stream>>>(block_max, time,
                                           out + 7 * (size_t)n, nblocks);
}

// Round 8
// 188.087 us; speedup vs baseline: 1.0687x; 1.0687x over previous
//
#include <hip/hip_runtime.h>

typedef float f32x4 __attribute__((ext_vector_type(4)));

#define V_THRESH 1.0f
#define TAU_REFRAC 0.1f
#define NBLOCKS 4096

// Process 4 lanes of a float4 (compile-time indexed -> registers).
__device__ __forceinline__ void neuron4(const f32x4 im, const f32x4 me,
                                        const f32x4 rf, const f32x4 pl,
                                        const f32x4 ps, const f32x4 sc,
                                        float t, float t_end,
                                        f32x4& vsp, f32x4& vmem, f32x4& vrf,
                                        f32x4& vpl, f32x4& vps, f32x4& vsc,
                                        f32x4& vst, float& lmax) {
    #pragma unroll
    for (int j = 0; j < 4; ++j) {
        float imp = im[j], m0 = me[j], r0 = rf[j];
        float p0 = pl[j], s0 = ps[j], c0 = sc[j];
        float mi = (r0 > t) ? 0.0f : imp;      // masked impulse
        float nm = m0 + mi;                    // new_mem
        bool spiked = (nm >= V_THRESH);
        float sp = spiked ? 1.0f : 0.0f;
        float resid = nm - V_THRESH;
        float new_pl = resid - s0;             // two-step, matches reference rounding
        vsp[j]  = sp * V_THRESH;
        vmem[j] = nm - V_THRESH * sp;          // reset by subtraction
        vpl[j]  = spiked ? new_pl : p0;
        vps[j]  = spiked ? (s0 + new_pl) : s0;
        vrf[j]  = spiked ? t_end : r0;
        float c1 = c0 + sp;
        vsc[j]  = c1;
        vst[j]  = t * sp;
        lmax = fmaxf(lmax, c1);
    }
}

__global__ __launch_bounds__(256) void spike_kernel(
    const f32x4* __restrict__ impulse,
    const f32x4* __restrict__ mem,
    const f32x4* __restrict__ refrac,
    const f32x4* __restrict__ payloads,
    const f32x4* __restrict__ paysum,
    const f32x4* __restrict__ spikecounts,
    const float* __restrict__ time,
    f32x4* __restrict__ out,           // 7 contiguous planes, n4 float4 each
    float* __restrict__ block_max,     // ws: one slot per block, always written
    int n4)
{
    const float t = time[0];
    const float t_end = t + TAU_REFRAC;

    f32x4* __restrict__ o_sp  = out;
    f32x4* __restrict__ o_mem = out + (size_t)n4;
    f32x4* __restrict__ o_rf  = out + 2 * (size_t)n4;
    f32x4* __restrict__ o_pl  = out + 3 * (size_t)n4;
    f32x4* __restrict__ o_ps  = out + 4 * (size_t)n4;
    f32x4* __restrict__ o_sc  = out + 5 * (size_t)n4;
    f32x4* __restrict__ o_st  = out + 6 * (size_t)n4;

    float lmax = -__builtin_inff();
    const size_t stride = (size_t)gridDim.x * blockDim.x;   // 1048576
    for (size_t i = (size_t)blockIdx.x * blockDim.x + threadIdx.x;
         i < (size_t)n4; i += stride) {                      // 4 iterations
        f32x4 im = impulse[i];
        f32x4 me = mem[i];
        f32x4 rf = refrac[i];
        f32x4 pl = payloads[i];
        f32x4 ps = paysum[i];
        f32x4 sc = spikecounts[i];
        f32x4 vsp, vmem, vrf, vpl, vps, vsc, vst;

        neuron4(im, me, rf, pl, ps, sc, t, t_end,
                vsp, vmem, vrf, vpl, vps, vsc, vst, lmax);

        o_sp[i]  = vsp;
        o_mem[i] = vmem;
        o_rf[i]  = vrf;
        o_pl[i]  = vpl;
        o_ps[i]  = vps;
        o_sc[i]  = vsc;
        o_st[i]  = vst;
    }

    // Block-level max reduce: wave butterfly -> LDS -> thread 0 stores.
    #pragma unroll
    for (int off = 32; off > 0; off >>= 1)
        lmax = fmaxf(lmax, __shfl_xor(lmax, off));

    __shared__ float wmax[4];
    if ((threadIdx.x & 63) == 0)
        wmax[threadIdx.x >> 6] = lmax;
    __syncthreads();
    if (threadIdx.x == 0) {
        float m = fmaxf(fmaxf(wmax[0], wmax[1]), fmaxf(wmax[2], wmax[3]));
        block_max[blockIdx.x] = m;
    }
}

__global__ __launch_bounds__(256) void finalize_kernel(
    const float* __restrict__ block_max,
    const float* __restrict__ time,
    float* __restrict__ out_scalar,
    int nblocks)
{
    float lmax = -__builtin_inff();
    for (int i = threadIdx.x; i < nblocks; i += 256)
        lmax = fmaxf(lmax, block_max[i]);
    #pragma unroll
    for (int off = 32; off > 0; off >>= 1)
        lmax = fmaxf(lmax, __shfl_xor(lmax, off));
    __shared__ float wmax[4];
    if ((threadIdx.x & 63) == 0)
        wmax[threadIdx.x >> 6] = lmax;
    __syncthreads();
    if (threadIdx.x == 0) {
        float m = fmaxf(fmaxf(wmax[0], wmax[1]), fmaxf(wmax[2], wmax[3]));
        out_scalar[0] = m * (1.0f / time[0]);
    }
}

extern "C" void kernel_launch(void* const* d_in, const int* in_sizes, int n_in,
                              void* d_out, int out_size, void* d_ws, size_t ws_size,
                              hipStream_t stream) {
    const f32x4* impulse     = (const f32x4*)d_in[0];
    const f32x4* mem         = (const f32x4*)d_in[1];
    const f32x4* refrac      = (const f32x4*)d_in[2];
    const f32x4* payloads    = (const f32x4*)d_in[3];
    const f32x4* paysum      = (const f32x4*)d_in[4];
    const f32x4* spikecounts = (const f32x4*)d_in[5];
    const float* time        = (const float*)d_in[6];

    const int n  = in_sizes[0];      // 16777216
    const int n4 = n / 4;            // 4194304
    float* out = (float*)d_out;
    float* block_max = (float*)d_ws; // NBLOCKS floats, fully rewritten each call

    spike_kernel<<<NBLOCKS, 256, 0, stream>>>(impulse, mem, refrac, payloads,
                                              paysum, spikecounts, time,
                                              (f32x4*)out, block_max, n4);
    finalize_kernel<<<1, 256, 0, stream>>>(block_max, time,
                                           out + 7 * (size_t)n, NBLOCKS);
}

// Round 9
// 180.937 us; speedup vs baseline: 1.1109x; 1.0395x over previous
//
#include <hip/hip_runtime.h>

typedef float f32x4 __attribute__((ext_vector_type(4)));

#define V_THRESH 1.0f
#define TAU_REFRAC 0.1f
#define NBLOCKS 2048

// Process 4 lanes of a float4 (compile-time indexed -> registers).
__device__ __forceinline__ void neuron4(const f32x4 im, const f32x4 me,
                                        const f32x4 rf, const f32x4 pl,
                                        const f32x4 ps, const f32x4 sc,
                                        float t, float t_end,
                                        f32x4& vsp, f32x4& vmem, f32x4& vrf,
                                        f32x4& vpl, f32x4& vps, f32x4& vsc,
                                        f32x4& vst, float& lmax) {
    #pragma unroll
    for (int j = 0; j < 4; ++j) {
        float imp = im[j], m0 = me[j], r0 = rf[j];
        float p0 = pl[j], s0 = ps[j], c0 = sc[j];
        float mi = (r0 > t) ? 0.0f : imp;      // masked impulse
        float nm = m0 + mi;                    // new_mem
        bool spiked = (nm >= V_THRESH);
        float sp = spiked ? 1.0f : 0.0f;
        float resid = nm - V_THRESH;
        float new_pl = resid - s0;             // two-step, matches reference rounding
        vsp[j]  = sp * V_THRESH;
        vmem[j] = nm - V_THRESH * sp;          // reset by subtraction
        vpl[j]  = spiked ? new_pl : p0;
        vps[j]  = spiked ? (s0 + new_pl) : s0;
        vrf[j]  = spiked ? t_end : r0;
        float c1 = c0 + sp;
        vsc[j]  = c1;
        vst[j]  = t * sp;
        lmax = fmaxf(lmax, c1);
    }
}

__global__ __launch_bounds__(256) void spike_kernel(
    const f32x4* __restrict__ impulse,
    const f32x4* __restrict__ mem,
    const f32x4* __restrict__ refrac,
    const f32x4* __restrict__ payloads,
    const f32x4* __restrict__ paysum,
    const f32x4* __restrict__ spikecounts,
    const float* __restrict__ time,
    f32x4* __restrict__ out,           // 7 contiguous planes, n4 float4 each
    float* __restrict__ block_max,     // ws: one slot per block, always written
    int n4)
{
    const float t = time[0];
    const float t_end = t + TAU_REFRAC;

    f32x4* __restrict__ o_sp  = out;
    f32x4* __restrict__ o_mem = out + (size_t)n4;
    f32x4* __restrict__ o_rf  = out + 2 * (size_t)n4;
    f32x4* __restrict__ o_pl  = out + 3 * (size_t)n4;
    f32x4* __restrict__ o_ps  = out + 4 * (size_t)n4;
    f32x4* __restrict__ o_sc  = out + 5 * (size_t)n4;
    f32x4* __restrict__ o_st  = out + 6 * (size_t)n4;

    float lmax = -__builtin_inff();
    const size_t stride = (size_t)gridDim.x * blockDim.x;   // 524288
    size_t i = (size_t)blockIdx.x * blockDim.x + threadIdx.x;

    // Main: 2-wide software pipeline — issue 12 loads before any store.
    for (; i + stride < (size_t)n4; i += 2 * stride) {
        const size_t i0 = i, i1 = i + stride;
        f32x4 imA = impulse[i0],     imB = impulse[i1];
        f32x4 meA = mem[i0],         meB = mem[i1];
        f32x4 rfA = refrac[i0],      rfB = refrac[i1];
        f32x4 plA = payloads[i0],    plB = payloads[i1];
        f32x4 psA = paysum[i0],      psB = paysum[i1];
        f32x4 scA = spikecounts[i0], scB = spikecounts[i1];

        f32x4 vspA, vmemA, vrfA, vplA, vpsA, vscA, vstA;
        f32x4 vspB, vmemB, vrfB, vplB, vpsB, vscB, vstB;
        neuron4(imA, meA, rfA, plA, psA, scA, t, t_end,
                vspA, vmemA, vrfA, vplA, vpsA, vscA, vstA, lmax);
        neuron4(imB, meB, rfB, plB, psB, scB, t, t_end,
                vspB, vmemB, vrfB, vplB, vpsB, vscB, vstB, lmax);

        __builtin_nontemporal_store(vspA,  &o_sp[i0]);
        __builtin_nontemporal_store(vspB,  &o_sp[i1]);
        __builtin_nontemporal_store(vmemA, &o_mem[i0]);
        __builtin_nontemporal_store(vmemB, &o_mem[i1]);
        __builtin_nontemporal_store(vrfA,  &o_rf[i0]);
        __builtin_nontemporal_store(vrfB,  &o_rf[i1]);
        __builtin_nontemporal_store(vplA,  &o_pl[i0]);
        __builtin_nontemporal_store(vplB,  &o_pl[i1]);
        __builtin_nontemporal_store(vpsA,  &o_ps[i0]);
        __builtin_nontemporal_store(vpsB,  &o_ps[i1]);
        __builtin_nontemporal_store(vscA,  &o_sc[i0]);
        __builtin_nontemporal_store(vscB,  &o_sc[i1]);
        __builtin_nontemporal_store(vstA,  &o_st[i0]);
        __builtin_nontemporal_store(vstB,  &o_st[i1]);
    }
    // Tail (empty for the bench shape: 4194304 / 524288 = 8 exact strides).
    for (; i < (size_t)n4; i += stride) {
        f32x4 im = impulse[i], me = mem[i], rf = refrac[i];
        f32x4 pl = payloads[i], ps = paysum[i], sc = spikecounts[i];
        f32x4 vsp, vmem, vrf, vpl, vps, vsc, vst;
        neuron4(im, me, rf, pl, ps, sc, t, t_end,
                vsp, vmem, vrf, vpl, vps, vsc, vst, lmax);
        o_sp[i] = vsp; o_mem[i] = vmem; o_rf[i] = vrf; o_pl[i] = vpl;
        o_ps[i] = vps; o_sc[i] = vsc; o_st[i] = vst;
    }

    // Block-level max reduce: wave butterfly -> LDS -> thread 0 stores.
    #pragma unroll
    for (int off = 32; off > 0; off >>= 1)
        lmax = fmaxf(lmax, __shfl_xor(lmax, off));

    __shared__ float wmax[4];
    if ((threadIdx.x & 63) == 0)
        wmax[threadIdx.x >> 6] = lmax;
    __syncthreads();
    if (threadIdx.x == 0) {
        float m = fmaxf(fmaxf(wmax[0], wmax[1]), fmaxf(wmax[2], wmax[3]));
        block_max[blockIdx.x] = m;
    }
}

__global__ __launch_bounds__(256) void finalize_kernel(
    const float* __restrict__ block_max,
    const float* __restrict__ time,
    float* __restrict__ out_scalar,
    int nblocks)
{
    float lmax = -__builtin_inff();
    for (int i = threadIdx.x; i < nblocks; i += 256)
        lmax = fmaxf(lmax, block_max[i]);
    #pragma unroll
    for (int off = 32; off > 0; off >>= 1)
        lmax = fmaxf(lmax, __shfl_xor(lmax, off));
    __shared__ float wmax[4];
    if ((threadIdx.x & 63) == 0)
        wmax[threadIdx.x >> 6] = lmax;
    __syncthreads();
    if (threadIdx.x == 0) {
        float m = fmaxf(fmaxf(wmax[0], wmax[1]), fmaxf(wmax[2], wmax[3]));
        out_scalar[0] = m * (1.0f / time[0]);
    }
}

extern "C" void kernel_launch(void* const* d_in, const int* in_sizes, int n_in,
                              void* d_out, int out_size, void* d_ws, size_t ws_size,
                              hipStream_t stream) {
    const f32x4* impulse     = (const f32x4*)d_in[0];
    const f32x4* mem         = (const f32x4*)d_in[1];
    const f32x4* refrac      = (const f32x4*)d_in[2];
    const f32x4* payloads    = (const f32x4*)d_in[3];
    const f32x4* paysum      = (const f32x4*)d_in[4];
    const f32x4* spikecounts = (const f32x4*)d_in[5];
    const float* time        = (const float*)d_in[6];

    const int n  = in_sizes[0];      // 16777216
    const int n4 = n / 4;            // 4194304
    float* out = (float*)d_out;
    float* block_max = (float*)d_ws; // NBLOCKS floats, fully rewritten each call

    spike_kernel<<<NBLOCKS, 256, 0, stream>>>(impulse, mem, refrac, payloads,
                                              paysum, spikecounts, time,
                                              (f32x4*)out, block_max, n4);
    finalize_kernel<<<1, 256, 0, stream>>>(block_max, time,
                                           out + 7 * (size_t)n, NBLOCKS);
}